// Round 1
// 127.653 us; speedup vs baseline: 1.1152x; 1.1152x over previous
//
#include <hip/hip_runtime.h>

// NearestEmbed (VQ argmin + gather), MI355X gfx950.  Round 4.
// x: (B=64, D=64, H=32, W=32) fp32 ; emb: (D=64, K=512) fp32
// out0: quant (B,D,H,W) fp32 ; out1: argmin (B,H,W) as fp32 values.
//
// R4: register-blocked fp32 GEMM structure (R3 post-mortem: VGPR_Count=48
// proved the x row was NOT register-resident -> 8x reload; scalar emb path
// stalled on K$-miss latency; VALU issue was 2.2x the FMA work).
//  * Both operands staged in LDS; hot loop = 3x ds_read_b128 (compile-time
//    offsets) + 32 v_fmac_f32 per d-step per thread. No s_loads, no per-step
//    address VALU.
//  * Thread tile 4 rows x 8 codes; block 256 thr = 64 rows x 128-code chunk;
//    4 chunks cover K=512. LDS 51.5 KB -> 3 blocks/CU, 12 waves/CU.
//  * Score arithmetic bitwise-identical to R3 (d-ascending fmaf chain, then
//    fmaf(-2,acc,e2)); first-index tie-break preserved -> absmax stays 0.
//  * Argmin merge: shfl_xor butterfly across the 16 code-threads.

constexpr int D    = 64;
constexpr int K    = 512;
constexpr int HW   = 1024;   // 32*32
constexpr int ROWS = 64;     // rows per block
constexpr int CK   = 128;    // codes per chunk
constexpr int NCH  = K / CK; // 4

__global__ __launch_bounds__(256, 3) void vq_kernel(
    const float* __restrict__ x,
    const float* __restrict__ emb,
    float* __restrict__ out_q,
    float* __restrict__ out_idx)
{
    __shared__ float xs[D][ROWS];   // 16 KB  xs[d][row]
    __shared__ float es[D][CK];     // 32 KB  es[d][code-in-chunk]
    __shared__ float e2s[K];        //  2 KB
    __shared__ int   kfin[ROWS];

    const int tid = threadIdx.x;
    const int ct  = tid & 15;       // code-thread: owns 8 codes of the chunk
    const int rg  = tid >> 4;       // row-group: owns 4 rows
    const int r0  = blockIdx.x * ROWS;
    const int b   = r0 >> 10;
    const int n0  = r0 & (HW - 1);

    const float* xg = x + ((size_t)b * D) * HW + n0;

    // ---- ||e_k||^2 : 2 codes per thread, coalesced (also warms L2) ----
    #pragma unroll
    for (int h = 0; h < 2; ++h) {
        const int k = h * 256 + tid;
        float s = 0.f;
        #pragma unroll
        for (int d = 0; d < D; ++d) {
            const float v = emb[d * K + k];
            s = fmaf(v, v, s);
        }
        e2s[k] = s;
    }

    // ---- stage x tile (64 d-planes x 64 rows), 4 x float4 per thread ----
    #pragma unroll
    for (int p = 0; p < 4; ++p) {
        const int li = p * 256 + tid;
        const int d  = li >> 4;
        const int r4 = (li & 15) << 2;
        const float4 v = *reinterpret_cast<const float4*>(xg + (size_t)d * HW + r4);
        *reinterpret_cast<float4*>(&xs[d][r4]) = v;
    }

    float best[4] = {3.4e38f, 3.4e38f, 3.4e38f, 3.4e38f};
    int   bidx[4] = {0, 0, 0, 0};

    for (int ch = 0; ch < NCH; ++ch) {
        __syncthreads();   // prev-chunk readers of es done (ch=0: no-op hazard-wise)

        // stage emb chunk (64 d x 128 codes), 8 x float4 per thread
        #pragma unroll
        for (int p = 0; p < 8; ++p) {
            const int li = p * 256 + tid;
            const int d  = li >> 5;
            const int c4 = (li & 31) << 2;
            const float4 v = *reinterpret_cast<const float4*>(emb + d * K + ch * CK + c4);
            *reinterpret_cast<float4*>(&es[d][c4]) = v;
        }
        __syncthreads();   // es (and on ch=0: xs, e2s) visible

        float acc[4][8];
        #pragma unroll
        for (int j = 0; j < 4; ++j)
            #pragma unroll
            for (int i = 0; i < 8; ++i) acc[j][i] = 0.f;

        // hot loop: per d-step 3x ds_read_b128 (imm offsets) + 32 fmac
        #pragma unroll
        for (int d = 0; d < D; ++d) {
            const float4 xv  = *reinterpret_cast<const float4*>(&xs[d][rg << 2]);
            const float4 ev0 = *reinterpret_cast<const float4*>(&es[d][ct << 3]);
            const float4 ev1 = *reinterpret_cast<const float4*>(&es[d][(ct << 3) + 4]);
            const float* xf  = reinterpret_cast<const float*>(&xv);
            const float* ef0 = reinterpret_cast<const float*>(&ev0);
            const float* ef1 = reinterpret_cast<const float*>(&ev1);
            #pragma unroll
            for (int j = 0; j < 4; ++j) {
                const float xj = xf[j];
                #pragma unroll
                for (int i = 0; i < 4; ++i) {
                    acc[j][i]     = fmaf(xj, ef0[i], acc[j][i]);
                    acc[j][i + 4] = fmaf(xj, ef1[i], acc[j][i + 4]);
                }
            }
        }

        // scoring: s = e2 - 2*acc  (identical fp32 chain to R3)
        const int kb = ch * CK + (ct << 3);
        const float4 q0 = *reinterpret_cast<const float4*>(&e2s[kb]);
        const float4 q1 = *reinterpret_cast<const float4*>(&e2s[kb + 4]);
        const float* qf0 = reinterpret_cast<const float*>(&q0);
        const float* qf1 = reinterpret_cast<const float*>(&q1);
        #pragma unroll
        for (int j = 0; j < 4; ++j) {
            #pragma unroll
            for (int i = 0; i < 8; ++i) {
                const float e2 = (i < 4) ? qf0[i] : qf1[i - 4];
                const float s  = fmaf(-2.f, acc[j][i], e2);
                if (s < best[j]) { best[j] = s; bidx[j] = kb + i; }  // strict <: first index
            }
        }
    }

    // ---- merge across the 16 code-threads (lanes tid^{1,2,4,8} share rg) ----
    #pragma unroll
    for (int m = 1; m < 16; m <<= 1) {
        #pragma unroll
        for (int j = 0; j < 4; ++j) {
            const float ob = __shfl_xor(best[j], m, 64);
            const int   oi = __shfl_xor(bidx[j], m, 64);
            if (ob < best[j] || (ob == best[j] && oi < bidx[j])) {
                best[j] = ob; bidx[j] = oi;   // lowest index wins exact ties
            }
        }
    }

    if (ct == 0) {
        #pragma unroll
        for (int j = 0; j < 4; ++j) {
            kfin[(rg << 2) + j] = bidx[j];
            __builtin_nontemporal_store((float)bidx[j], &out_idx[r0 + (rg << 2) + j]);
        }
    }
    __syncthreads();

    // ---- epilogue: gather emb column, coalesced nontemporal stores ----
    const int row = tid & 63;
    const int dg  = tid >> 6;            // 16 d-planes per thread
    const int kq  = kfin[row];
    float* oq = out_q + ((size_t)b * D) * HW + n0 + row;
    #pragma unroll
    for (int j = 0; j < 16; ++j) {
        const int d = (dg << 4) + j;
        // emb gather is per-lane scattered 4B but L2-hot (128 KB table);
        // stores: consecutive rows across lanes -> full 256B lines.
        __builtin_nontemporal_store(emb[d * K + kq], &oq[(size_t)d * HW]);
    }
}

extern "C" void kernel_launch(void* const* d_in, const int* in_sizes, int n_in,
                              void* d_out, int out_size, void* d_ws, size_t ws_size,
                              hipStream_t stream)
{
    const float* x   = (const float*)d_in[0];   // 4194304 floats
    const float* emb = (const float*)d_in[1];   // 32768 floats

    float* out_q   = (float*)d_out;                     // 4194304 floats
    float* out_idx = out_q + (size_t)64 * 64 * 1024;    // 65536 floats

    // 65536 rows / 64 rows-per-block = 1024 blocks of 256 threads
    // (LDS 51.5 KB -> 3 blocks/CU, 12 waves/CU)
    vq_kernel<<<1024, 256, 0, stream>>>(x, emb, out_q, out_idx);
}

// Round 2
// 121.254 us; speedup vs baseline: 1.1740x; 1.0528x over previous
//
#include <hip/hip_runtime.h>

// NearestEmbed (VQ argmin + gather), MI355X gfx950.  Round 5.
// x: (B=64, D=64, H=32, W=32) fp32 ; emb: (D=64, K=512) fp32
// out0: quant (B,D,H,W) fp32 ; out1: argmin (B,H,W) as fp32.
//
// R5 (R4 post-mortem: LDS pipe ~100% busy; es reads 4-way bank-conflicted
// (8.5M conflict cycles); 1.5 B/MAC LDS demand > LDS delivery):
//  * 8x8 thread tile -> 1.0 B/MAC, 4 ds_read_b128 per 64 FMAs.
//  * Strided ownership both sides: rows {rg*4..+3, 64+rg*4..+3}, codes
//    {ct*4..+3, 64+ct*4..+3} -> all hot reads 16-byte stride = 2-way bank
//    aliasing = free (m136). Hot loop conflict-free.
//  * Staging via __builtin_amdgcn_global_load_lds (dest linear li*16 =
//    wave-uniform base + lane*16): no ds_write traffic, no VGPR roundtrip.
//  * Score chain unchanged (d-ascending fmaf, then fmaf(-2,acc,e2));
//    ascending in-thread code scan + index-compare merge keeps first-index
//    tie-break -> absmax stays 0.

constexpr int D    = 64;
constexpr int K    = 512;
constexpr int HW   = 1024;   // 32*32
constexpr int ROWS = 128;    // rows per block
constexpr int CK   = 128;    // codes per chunk
constexpr int NCH  = K / CK; // 4

__device__ __forceinline__ void gload16(const float* g, float* l) {
    __builtin_amdgcn_global_load_lds(
        (const __attribute__((address_space(1))) void*)g,
        (__attribute__((address_space(3))) void*)l,
        16, 0, 0);
}

__global__ __launch_bounds__(256, 2) void vq_kernel(
    const float* __restrict__ x,
    const float* __restrict__ emb,
    float* __restrict__ out_q,
    float* __restrict__ out_idx)
{
    __shared__ float xs[D][ROWS];   // 32 KB  xs[d][row]
    __shared__ float es[D][CK];     // 32 KB  es[d][code-in-chunk]
    __shared__ float e2s[K];        //  2 KB
    __shared__ int   kfin[ROWS];

    const int tid = threadIdx.x;
    const int ct  = tid & 15;       // code-thread
    const int rg  = tid >> 4;       // row-group
    const int r0  = blockIdx.x * ROWS;
    const int b   = r0 >> 10;
    const int n0  = r0 & (HW - 1);

    const float* xg = x + ((size_t)b * D) * HW + n0;

    // ---- stage x tile (64 d x 128 rows) via global_load_lds ----
    // dest byte = li*16 (linear), src coalesced per 32-lane half.
    #pragma unroll
    for (int p = 0; p < 8; ++p) {
        const int li = p * 256 + tid;
        const int d  = li >> 5;            // 32 float4 per 128-float row
        const int r4 = (li & 31) << 2;
        gload16(xg + (size_t)d * HW + r4, &xs[d][r4]);
    }

    // ---- ||e_k||^2 : 2 codes per thread, coalesced (warms L2) ----
    #pragma unroll
    for (int h = 0; h < 2; ++h) {
        const int k = h * 256 + tid;
        float s = 0.f;
        #pragma unroll
        for (int d = 0; d < D; ++d) {
            const float v = emb[d * K + k];
            s = fmaf(v, v, s);
        }
        e2s[k] = s;
    }

    float best[8];
    int   bidx[8];
    #pragma unroll
    for (int j = 0; j < 8; ++j) { best[j] = 3.4e38f; bidx[j] = 0; }

    #pragma unroll 1
    for (int ch = 0; ch < NCH; ++ch) {
        __syncthreads();   // prev-chunk readers of es done

        // stage emb chunk (64 d x 128 codes) via global_load_lds
        #pragma unroll
        for (int p = 0; p < 8; ++p) {
            const int li = p * 256 + tid;
            const int d  = li >> 5;
            const int c4 = (li & 31) << 2;
            gload16(emb + d * K + ch * CK + c4, &es[d][c4]);
        }
        __syncthreads();   // drains vmcnt: es (and on ch=0: xs) visible

        float acc[8][8];
        #pragma unroll
        for (int j = 0; j < 8; ++j)
            #pragma unroll
            for (int i = 0; i < 8; ++i) acc[j][i] = 0.f;

        // hot loop: 4x ds_read_b128 (16B-stride addrs, conflict-free) + 64 fmac
        #pragma unroll
        for (int d = 0; d < D; ++d) {
            const float4 xv0 = *reinterpret_cast<const float4*>(&xs[d][rg << 2]);
            const float4 xv1 = *reinterpret_cast<const float4*>(&xs[d][64 + (rg << 2)]);
            const float4 ev0 = *reinterpret_cast<const float4*>(&es[d][ct << 2]);
            const float4 ev1 = *reinterpret_cast<const float4*>(&es[d][64 + (ct << 2)]);
            const float* xa = reinterpret_cast<const float*>(&xv0);
            const float* xb = reinterpret_cast<const float*>(&xv1);
            const float* ea = reinterpret_cast<const float*>(&ev0);
            const float* eb = reinterpret_cast<const float*>(&ev1);
            #pragma unroll
            for (int j = 0; j < 4; ++j) {
                const float x0 = xa[j];
                const float x1 = xb[j];
                #pragma unroll
                for (int i = 0; i < 4; ++i) {
                    acc[j][i]         = fmaf(x0, ea[i], acc[j][i]);
                    acc[j][i + 4]     = fmaf(x0, eb[i], acc[j][i + 4]);
                    acc[j + 4][i]     = fmaf(x1, ea[i], acc[j + 4][i]);
                    acc[j + 4][i + 4] = fmaf(x1, eb[i], acc[j + 4][i + 4]);
                }
            }
        }

        // scoring: s = e2 - 2*acc (identical fp32 chain); in-thread scan is
        // ascending in code index (ct*4+i then 64+ct*4+i), strict < = first.
        const int kb = ch * CK;
        const float4 q0 = *reinterpret_cast<const float4*>(&e2s[kb + (ct << 2)]);
        const float4 q1 = *reinterpret_cast<const float4*>(&e2s[kb + 64 + (ct << 2)]);
        const float* qa = reinterpret_cast<const float*>(&q0);
        const float* qb = reinterpret_cast<const float*>(&q1);
        #pragma unroll
        for (int j = 0; j < 8; ++j) {
            #pragma unroll
            for (int i = 0; i < 4; ++i) {
                const float s0 = fmaf(-2.f, acc[j][i], qa[i]);
                if (s0 < best[j]) { best[j] = s0; bidx[j] = kb + (ct << 2) + i; }
            }
            #pragma unroll
            for (int i = 0; i < 4; ++i) {
                const float s1 = fmaf(-2.f, acc[j][i + 4], qb[i]);
                if (s1 < best[j]) { best[j] = s1; bidx[j] = kb + 64 + (ct << 2) + i; }
            }
        }
    }

    // ---- merge across 16 code-threads (lane bits 0..3 = ct bits) ----
    #pragma unroll
    for (int m = 1; m < 16; m <<= 1) {
        #pragma unroll
        for (int j = 0; j < 8; ++j) {
            const float ob = __shfl_xor(best[j], m, 64);
            const int   oi = __shfl_xor(bidx[j], m, 64);
            if (ob < best[j] || (ob == best[j] && oi < bidx[j])) {
                best[j] = ob; bidx[j] = oi;   // lowest index wins exact ties
            }
        }
    }

    if (ct == 0) {
        #pragma unroll
        for (int j = 0; j < 8; ++j) {
            const int rloc = (j < 4) ? ((rg << 2) + j) : (64 + (rg << 2) + (j - 4));
            kfin[rloc] = bidx[j];
            __builtin_nontemporal_store((float)bidx[j], &out_idx[r0 + rloc]);
        }
    }
    __syncthreads();

    // ---- epilogue: gather emb column, coalesced nontemporal stores ----
    const int row = tid & 127;
    const int dg  = tid >> 7;            // 2 threads/row, 32 d-planes each
    const int kq  = kfin[row];
    float* oq = out_q + ((size_t)b * D) * HW + n0 + row;
    #pragma unroll
    for (int j = 0; j < 32; ++j) {
        const int d = (dg << 5) + j;
        // emb gather per-lane scattered 4B but L2-hot (128 KB table);
        // stores: consecutive rows across lanes -> full 256B lines.
        __builtin_nontemporal_store(emb[d * K + kq], &oq[(size_t)d * HW]);
    }
}

extern "C" void kernel_launch(void* const* d_in, const int* in_sizes, int n_in,
                              void* d_out, int out_size, void* d_ws, size_t ws_size,
                              hipStream_t stream)
{
    const float* x   = (const float*)d_in[0];   // 4194304 floats
    const float* emb = (const float*)d_in[1];   // 32768 floats

    float* out_q   = (float*)d_out;                     // 4194304 floats
    float* out_idx = out_q + (size_t)64 * 64 * 1024;    // 65536 floats

    // 65536 rows / 128 rows-per-block = 512 blocks of 256 threads
    // (LDS 66.5 KB -> 2 blocks/CU, 8 waves/CU)
    vq_kernel<<<512, 256, 0, stream>>>(x, emb, out_q, out_idx);
}